// Round 1
// 134.618 us; speedup vs baseline: 1.0729x; 1.0729x over previous
//
#include <hip/hip_runtime.h>
#include <hip/hip_bf16.h>
#include <stdint.h>

// Problem constants (B, L, D, T) = (2, 2048, 1536, 2)
#define B_ 2
#define L_ 2048
#define D_ 1536
#define NT (D_ / 64)   // 24 K-tiles of BK=64

typedef __attribute__((ext_vector_type(4))) float  f32x4;
typedef __attribute__((ext_vector_type(8))) __bf16 bf16x8;

__device__ __forceinline__ unsigned short f2bf(float f) {
  unsigned int u = __float_as_uint(f);
  u += 0x7fffu + ((u >> 16) & 1u);   // RNE
  return (unsigned short)(u >> 16);
}

// ---------------------------------------------------------------------------
// Stage 1: hs(fp32) -> X(bf16), and P[t] = hs * Wp[t] (bf16), t in {0,1}
// (unchanged: ~63 MB of traffic, near its HBM floor)
// ---------------------------------------------------------------------------
__global__ __launch_bounds__(256) void conv_kernel(
    const float* __restrict__ hs, const float* __restrict__ W,
    unsigned short* __restrict__ X, unsigned short* __restrict__ P) {
  const int idx  = blockIdx.x * 256 + threadIdx.x;
  const int base = idx * 4;
  const int d    = base % D_;
  const float4 h  = *(const float4*)(hs + base);
  const float4 w0 = *(const float4*)(W + d);
  const float4 w1 = *(const float4*)(W + 2 * D_ + d);
  ushort4 x, p0, p1;
  x.x  = f2bf(h.x);        x.y  = f2bf(h.y);        x.z  = f2bf(h.z);        x.w  = f2bf(h.w);
  p0.x = f2bf(h.x * w0.x); p0.y = f2bf(h.y * w0.y); p0.z = f2bf(h.z * w0.z); p0.w = f2bf(h.w * w0.w);
  p1.x = f2bf(h.x * w1.x); p1.y = f2bf(h.y * w1.y); p1.z = f2bf(h.z * w1.z); p1.w = f2bf(h.w * w1.w);
  *(ushort4*)(X + base) = x;
  *(ushort4*)(P + base) = p0;
  *(ushort4*)(P + (size_t)B_ * L_ * D_ + base) = p1;
}

// ---------------------------------------------------------------------------
// Stage 2: 256x256 8-phase GEMM (T1+T2+T3+T4+T5), t fused along M.
// A' = [P0 rows 0..127 ; P1 rows 0..127] (256 x K), B = X rows (256 x K).
// out[b,i,j,(t0,t1)] = P_t[b,i,:].X[b,j,:] + bias[t]
// 512 threads = 8 waves (2 x 4); per-wave C = 128x64 as 8x4 16x16 frags,
// m-frags 0-3 = t0 / 4-7 = t1 at the SAME i -> dense float2 epilogue.
// LDS: 2 buffers x 4 regions (A-half0, A-half1, B-half0, B-half1) x 16 KiB.
// Staging: global_load_lds dwordx4, linear LDS dest, inverse-swizzled global
// source; ds_read_b128 with byte ^= ((row&7)<<4) swizzle (conflict-free).
// Counted vmcnt: steady {p0:6, p1:6, p2:-, p3:4}; never drained to 0 in loop.
// ---------------------------------------------------------------------------
__device__ __forceinline__ void gload16(const unsigned short* g, unsigned short* l) {
  __builtin_amdgcn_global_load_lds(
      (const __attribute__((address_space(1))) unsigned int*)g,
      (__attribute__((address_space(3))) unsigned int*)l, 16, 0, 0);
}

#define A0OFF 0
#define A1OFF 8192
#define B0OFF 16384
#define B1OFF 24576

__global__ __launch_bounds__(512, 2) void gemm_kernel(
    const unsigned short* __restrict__ X, const unsigned short* __restrict__ P,
    const float* __restrict__ bias, float2* __restrict__ out) {
  __shared__ unsigned short lds[65536];   // 128 KiB

  const int tid = threadIdx.x;

  // ---- T1: XCD-aware bijective swizzle (256 % 8 == 0)
  const int id  = blockIdx.x;
  const int swz = (id & 7) * 32 + (id >> 3);
  const int bz  = swz >> 7;               // batch
  const int t2  = swz & 127;
  const int I0  = (t2 >> 3) * 128;        // 16 i-tiles
  const int J0  = (t2 & 7) * 256;         // 8 j-tiles

  const size_t planeB = (size_t)B_ * L_ * D_;
  const unsigned short* gA0 = P + (size_t)(bz * L_ + I0) * D_;   // P0 rows
  const unsigned short* gA1 = gA0 + planeB;                      // P1 rows
  const unsigned short* gB0 = X + (size_t)(bz * L_ + J0) * D_;   // X rows
  const unsigned short* gB1 = gB0 + (size_t)128 * D_;

  // ---- staging geometry: thread t, load l in {0,1}:
  // within-half row r = l*64 + (t>>3); stored chunk = t&7 holds logical
  // chunk (t&7)^(r&7)  (inverse of the read-side XOR swizzle).
  const int    sr    = tid >> 3;
  const int    sc    = (tid & 7) ^ (sr & 7);
  const size_t lgoff = (size_t)sr * D_ + (size_t)(sc * 8);
  const int    wuni  = (tid >> 6) * 512;   // wave-uniform LDS base (shorts)

  // ---- compute geometry
  const int lane = tid & 63;
  const int w    = tid >> 6;
  const int wr   = w & 1;        // 2 wave-rows
  const int wc   = w >> 1;       // 4 wave-cols
  const int lr   = lane & 15;
  const int q    = lane >> 4;
  const int swd  = lr & 7;
  const int csw0 = ((0 + q) ^ swd) * 8;    // kk=0 chunk, swizzled (shorts)
  const int csw1 = ((4 + q) ^ swd) * 8;    // kk=1
  int aRow[4], bRow[2];
#pragma unroll
  for (int m = 0; m < 4; ++m) aRow[m] = (wr * 64 + m * 16 + lr) * 64;
#pragma unroll
  for (int n = 0; n < 2; ++n) bRow[n] = (wc * 32 + n * 16 + lr) * 64;

  f32x4  acc[8][4] = {};
  bf16x8 aF[4][2], bF[2][2];

#define STG(REG, GBASE, KTN)                                                  \
  do {                                                                        \
    const unsigned short* g0 = (GBASE) + lgoff + (size_t)((KTN) * 64);        \
    gload16(g0,                 lds + (REG) + wuni);                          \
    gload16(g0 + (size_t)64 * D_, lds + (REG) + 4096 + wuni);                 \
  } while (0)

#define RDA(CB, MH)                                                           \
  do {                                                                        \
    _Pragma("unroll") for (int m = 0; m < 4; ++m) {                           \
      aF[m][0] = *(const bf16x8*)(lds + (CB) + (MH) * 8192 + aRow[m] + csw0); \
      aF[m][1] = *(const bf16x8*)(lds + (CB) + (MH) * 8192 + aRow[m] + csw1); \
    }                                                                         \
  } while (0)

#define RDB(CB, NH)                                                           \
  do {                                                                        \
    _Pragma("unroll") for (int n = 0; n < 2; ++n) {                           \
      bF[n][0] = *(const bf16x8*)(lds + (CB) + 16384 + (NH) * 8192 + bRow[n] + csw0); \
      bF[n][1] = *(const bf16x8*)(lds + (CB) + 16384 + (NH) * 8192 + bRow[n] + csw1); \
    }                                                                         \
  } while (0)

#define MM(MH, NH)                                                            \
  do {                                                                        \
    _Pragma("unroll") for (int kk = 0; kk < 2; ++kk)                          \
    _Pragma("unroll") for (int m = 0; m < 4; ++m)                             \
    _Pragma("unroll") for (int n = 0; n < 2; ++n)                             \
      acc[(MH) * 4 + m][(NH) * 2 + n] = __builtin_amdgcn_mfma_f32_16x16x32_bf16( \
          aF[m][kk], bF[n][kk], acc[(MH) * 4 + m][(NH) * 2 + n], 0, 0, 0);    \
  } while (0)

#define BAR()   __builtin_amdgcn_s_barrier()
#define LGKM0() asm volatile("s_waitcnt lgkmcnt(0)" ::: "memory")
#define WVM(n)  asm volatile("s_waitcnt vmcnt(" #n ")" ::: "memory")
#define PRIO1() __builtin_amdgcn_s_setprio(1)
#define PRIO0() __builtin_amdgcn_s_setprio(0)

  // Phase order per K-tile: Q(0,0) Q(0,1) Q(1,1) Q(1,0).
  // Stage of kt+1 (into NB): A0,B0 @p0 ; B1 @p1 ; A1 @p2 ; - @p3.
#define KSTEP(CB, NB, KTN)                                                    \
  do {                                                                        \
    /* p0 */                                                                  \
    RDA(CB, 0); RDB(CB, 0);                                                   \
    STG((NB) + A0OFF, gA0, KTN); STG((NB) + B0OFF, gB0, KTN);                 \
    BAR(); LGKM0();                                                           \
    PRIO1(); MM(0, 0); PRIO0();                                               \
    WVM(6); BAR();                                                            \
    /* p1 */                                                                  \
    RDB(CB, 1);                                                               \
    STG((NB) + B1OFF, gB1, KTN);                                              \
    BAR(); LGKM0();                                                           \
    PRIO1(); MM(0, 1); PRIO0();                                               \
    WVM(6); BAR();                                                            \
    /* p2 */                                                                  \
    RDA(CB, 1);                                                               \
    STG((NB) + A1OFF, gA1, KTN);                                              \
    BAR(); LGKM0();                                                           \
    PRIO1(); MM(1, 1); PRIO0();                                               \
    BAR();                                                                    \
    /* p3 (B-half0 re-read; no staging) */                                    \
    RDB(CB, 0);                                                               \
    BAR(); LGKM0();                                                           \
    PRIO1(); MM(1, 0); PRIO0();                                               \
    WVM(4); BAR();                                                            \
  } while (0)

#define KTAIL(CB)                                                             \
  do {                                                                        \
    RDA(CB, 0); RDB(CB, 0);                                                   \
    BAR(); LGKM0();                                                           \
    PRIO1(); MM(0, 0); PRIO0();                                               \
    WVM(2); BAR();                                                            \
    RDB(CB, 1);                                                               \
    BAR(); LGKM0();                                                           \
    PRIO1(); MM(0, 1); PRIO0();                                               \
    WVM(0); BAR();                                                            \
    RDA(CB, 1);                                                               \
    BAR(); LGKM0();                                                           \
    PRIO1(); MM(1, 1); PRIO0();                                               \
    BAR();                                                                    \
    RDB(CB, 0);                                                               \
    LGKM0();                                                                  \
    PRIO1(); MM(1, 0); PRIO0();                                               \
  } while (0)

  // ---- prologue: K-tile 0 into buffer 0, issued in wait-order
  STG(A0OFF, gA0, 0); STG(B0OFF, gB0, 0);
  STG(B1OFF, gB1, 0);
  STG(A1OFF, gA1, 0);
  WVM(4); BAR();

  // ---- main loop: kt = 0..21 (paired), 22 (stages 23), tail 23
#pragma unroll 1
  for (int it = 0; it < 11; ++it) {
    const int kt0 = 2 * it;
    KSTEP(0,     32768, kt0 + 1);
    KSTEP(32768, 0,     kt0 + 2);
  }
  KSTEP(0, 32768, 23);
  KTAIL(32768);

#undef KSTEP
#undef KTAIL
#undef STG
#undef RDA
#undef RDB
#undef MM

  // ---- epilogue: C/D layout col(j)=lane&15, row(i)=q*4+reg.
  // acc[m][.] (m<4) = t0, acc[m+4][.] = t1 at the same i -> dense float2.
  const float bias0 = bias[0], bias1 = bias[1];
#pragma unroll
  for (int m = 0; m < 4; ++m) {
#pragma unroll
    for (int r = 0; r < 4; ++r) {
      const int i = I0 + wr * 64 + m * 16 + q * 4 + r;
      float2* orow = out + (size_t)(bz * L_ + i) * L_;
#pragma unroll
      for (int n = 0; n < 4; ++n) {
        const int j = J0 + (n >> 1) * 128 + wc * 32 + (n & 1) * 16 + lr;
        float2 v;
        v.x = acc[m][n][r] + bias0;
        v.y = acc[m + 4][n][r] + bias1;
        orow[j] = v;
      }
    }
  }
}

extern "C" void kernel_launch(void* const* d_in, const int* in_sizes, int n_in,
                              void* d_out, int out_size, void* d_ws, size_t ws_size,
                              hipStream_t stream) {
  const float* hs   = (const float*)d_in[0];
  const float* W    = (const float*)d_in[1];
  const float* bias = (const float*)d_in[2];

  unsigned short* X = (unsigned short*)d_ws;                 // B*L*D bf16
  unsigned short* P = X + (size_t)B_ * L_ * D_;              // T*B*L*D bf16

  const int nconv = (B_ * L_ * D_ / 4) / 256;                // 6144 blocks
  conv_kernel<<<nconv, 256, 0, stream>>>(hs, W, X, P);

  gemm_kernel<<<256, 512, 0, stream>>>(X, P, bias, (float2*)d_out);
}